// Round 2
// baseline (132.943 us; speedup 1.0000x reference)
//
#include <hip/hip_runtime.h>
#include <hip/hip_bf16.h>

#define NROWS 8192
#define KDIM  512
#define NT    64                 // 8192/128 tiles per dim
#define NBLK  (NT*(NT+1)/2)      // upper-triangle tile pairs = 2080

typedef __attribute__((ext_vector_type(16))) float f32x16;

__device__ __forceinline__ void async_copy16(const void* g, void* l) {
    __builtin_amdgcn_global_load_lds((const __attribute__((address_space(1))) void*)g,
                                     (__attribute__((address_space(3))) void*)l,
                                     16, 0, 0);
}

// z (fp32) -> fp8 e4m3 into workspace, sq[i] = ||z_i||^2 in fp32, zero acc+cnt.
__global__ __launch_bounds__(256) void prep_kernel(const float* __restrict__ z,
                                                   unsigned char* __restrict__ zb,
                                                   float* __restrict__ sq,
                                                   float* __restrict__ acc,
                                                   unsigned* __restrict__ cnt) {
    int wave = threadIdx.x >> 6, lane = threadIdx.x & 63;
    int row = blockIdx.x * 4 + wave;
    const float* zr = z + (size_t)row * KDIM + lane * 8;
    float4 v0 = *(const float4*)zr;
    float4 v1 = *(const float4*)(zr + 4);
    float vals[8] = {v0.x, v0.y, v0.z, v0.w, v1.x, v1.y, v1.z, v1.w};
    float s = 0.f;
#pragma unroll
    for (int i = 0; i < 8; ++i) s += vals[i] * vals[i];
    int lo = __builtin_amdgcn_cvt_pk_fp8_f32(vals[0], vals[1], 0, false);
    lo     = __builtin_amdgcn_cvt_pk_fp8_f32(vals[2], vals[3], lo, true);
    int hi = __builtin_amdgcn_cvt_pk_fp8_f32(vals[4], vals[5], 0, false);
    hi     = __builtin_amdgcn_cvt_pk_fp8_f32(vals[6], vals[7], hi, true);
    int2 pk; pk.x = lo; pk.y = hi;
    *(int2*)(zb + (size_t)row * KDIM + lane * 8) = pk;
#pragma unroll
    for (int off = 32; off; off >>= 1) s += __shfl_down(s, off);
    if (lane == 0) sq[row] = s;
    if (blockIdx.x == 0 && threadIdx.x == 0) { acc[0] = 0.f; cnt[0] = 0u; }
}

// One 128x128 Gram tile per block (upper triangle), fp8 MFMA 32x32x16,
// fused exp epilogue, last-block-done computes the final log.
__global__ __launch_bounds__(256, 4) void gram_kernel(const unsigned char* __restrict__ zb,
                                                      const float* __restrict__ sq,
                                                      float* __restrict__ acc,
                                                      unsigned* __restrict__ cnt,
                                                      float* __restrict__ out) {
    __shared__ __align__(16) unsigned char Ash[128 * 128];   // 16 KB (128 rows x BK=128 fp8)
    __shared__ __align__(16) unsigned char Bsh[128 * 128];   // 16 KB

    int tid = threadIdx.x;
    int wave = tid >> 6, lane = tid & 63;
    int ln31 = lane & 31, khalf = lane >> 5;
    int wm = wave >> 1, wn = wave & 1;
    int sl = lane & 7;                 // row&7 swizzle key (row = ..32m + ln31)

    // linear block id -> (bi, bj), bi <= bj
    int rem = blockIdx.x, bi = 0;
    while (rem >= NT - bi) { rem -= NT - bi; ++bi; }
    int bj = bi + rem;

    // staging source precompute (k0-invariant)
    int c0 = tid;                      // chunks c0, c0+256, c0+512, c0+768
    const unsigned char* Agbase = zb + (size_t)(bi * 128) * KDIM;
    const unsigned char* Bgbase = zb + (size_t)(bj * 128) * KDIM;

    f32x16 accf[2][2];
#pragma unroll
    for (int mi = 0; mi < 2; ++mi)
#pragma unroll
        for (int ni = 0; ni < 2; ++ni)
#pragma unroll
            for (int r = 0; r < 16; ++r) accf[mi][ni][r] = 0.f;

    // LDS fragment base addresses (A row = wm*64 + mi*32 + ln31)
    const unsigned char* aB = Ash + (wm * 64 + ln31) * 128 + khalf * 8;
    const unsigned char* bB = Bsh + (wn * 64 + ln31) * 128 + khalf * 8;

    for (int k0 = 0; k0 < KDIM; k0 += 128) {
#pragma unroll
        for (int it = 0; it < 4; ++it) {
            int c = it * 256 + c0;
            int row = c >> 3, cc = c & 7;
            int sc = cc ^ (row & 7);
            async_copy16(Agbase + (size_t)row * KDIM + k0 + sc * 16, (unsigned char*)Ash + c * 16);
            async_copy16(Bgbase + (size_t)row * KDIM + k0 + sc * 16, (unsigned char*)Bsh + c * 16);
        }
        __syncthreads();

#pragma unroll
        for (int s = 0; s < 8; ++s) {
            int off = ((s ^ sl) * 16);
            long a0 = *(const long*)(aB + off);
            long a1 = *(const long*)(aB + off + 32 * 128);
            long b0 = *(const long*)(bB + off);
            long b1 = *(const long*)(bB + off + 32 * 128);
            accf[0][0] = __builtin_amdgcn_mfma_f32_32x32x16_fp8_fp8(a0, b0, accf[0][0], 0, 0, 0);
            accf[0][1] = __builtin_amdgcn_mfma_f32_32x32x16_fp8_fp8(a0, b1, accf[0][1], 0, 0, 0);
            accf[1][0] = __builtin_amdgcn_mfma_f32_32x32x16_fp8_fp8(a1, b0, accf[1][0], 0, 0, 0);
            accf[1][1] = __builtin_amdgcn_mfma_f32_32x32x16_fp8_fp8(a1, b1, accf[1][1], 0, 0, 0);
        }
        __syncthreads();
    }

    // ---- fused epilogue: exp(-D/tau) for gi<gj ----
    int rowBase = bi * 128 + wm * 64;
    int colBase = bj * 128 + wn * 64;
    float sqj[2] = { sq[colBase + ln31], sq[colBase + 32 + ln31] };

    float local = 0.f;
#pragma unroll
    for (int mi = 0; mi < 2; ++mi) {
#pragma unroll
        for (int reg = 0; reg < 16; ++reg) {
            int rowf = (reg & 3) + 8 * (reg >> 2) + 4 * khalf;   // C/D row (m74/m101)
            int gi = rowBase + mi * 32 + rowf;
            float sqi = sq[gi];
#pragma unroll
            for (int ni = 0; ni < 2; ++ni) {
                int gj = colBase + ni * 32 + ln31;               // C/D col = lane&31
                float d = sqi + sqj[ni] - 2.f * accf[mi][ni][reg];
                d = fmaxf(d, 0.f);
                float e = __expf(d * (-1.f / 100.f));
                local += (gi < gj) ? e : 0.f;
            }
        }
    }

#pragma unroll
    for (int off = 32; off; off >>= 1) local += __shfl_down(local, off);
    __shared__ float wsum[4];
    if (lane == 0) wsum[wave] = local;
    __syncthreads();
    if (tid == 0) {
        atomicAdd(acc, wsum[0] + wsum[1] + wsum[2] + wsum[3]);
        __threadfence();
        unsigned t = atomicAdd(cnt, 1u);
        if (t == NBLK - 1) {
            float total = 2.f * atomicAdd(acc, 0.f);   // coherent read of final sum
            out[0] = logf(total / ((float)NROWS * (float)(NROWS - 1)));
        }
    }
}

extern "C" void kernel_launch(void* const* d_in, const int* in_sizes, int n_in,
                              void* d_out, int out_size, void* d_ws, size_t ws_size,
                              hipStream_t stream) {
    const float* z = (const float*)d_in[0];
    float* out = (float*)d_out;
    unsigned char* zb = (unsigned char*)d_ws;                     // 8192*512 fp8 = 4 MB
    float* sq = (float*)((char*)d_ws + (size_t)NROWS * KDIM);     // 32 KB
    float* acc = sq + NROWS;                                      // 4 B
    unsigned* cnt = (unsigned*)(acc + 1);                         // 4 B

    prep_kernel<<<NROWS / 4, 256, 0, stream>>>(z, zb, sq, acc, cnt);
    gram_kernel<<<NBLK, 256, 0, stream>>>(zb, sq, acc, cnt, out);
}